// Round 2
// baseline (866.758 us; speedup 1.0000x reference)
//
#include <hip/hip_runtime.h>
#include <hip/hip_bf16.h>
#include <cstdio>

typedef __bf16 bf16;
typedef __attribute__((ext_vector_type(8))) __bf16 bf16x8;
typedef __attribute__((ext_vector_type(4))) float f32x4;

#define MFMA16(a, b, c) __builtin_amdgcn_mfma_f32_16x16x32_bf16((a), (b), (c), 0, 0, 0)

constexpr int Bb = 4, Nn = 2047, Cc = 1024, Hh = 16, Dd = 64;
constexpr int M_ROWS = Bb * Nn;      // 8188
constexpr float SCALE = 0.125f;      // D^-0.5
constexpr float NEG_BIG = -1e30f;    // finite sentinel (no inf anywhere)

__device__ inline bf16x8 bzero8() {
    bf16x8 v;
    for (int i = 0; i < 8; ++i) v[i] = (bf16)0.0f;
    return v;
}
__device__ inline f32x4 fzero4() {
    f32x4 v = {0.f, 0.f, 0.f, 0.f};
    return v;
}
// load 8 contiguous elems as bf16x8; fp32 source converts on the fly
__device__ inline bf16x8 load8(const float* p) {
    float4 a = *(const float4*)p;
    float4 b = *(const float4*)(p + 4);
    bf16x8 v;
    v[0] = (bf16)a.x; v[1] = (bf16)a.y; v[2] = (bf16)a.z; v[3] = (bf16)a.w;
    v[4] = (bf16)b.x; v[5] = (bf16)b.y; v[6] = (bf16)b.z; v[7] = (bf16)b.w;
    return v;
}
__device__ inline bf16x8 load8(const bf16* p) { return *(const bf16x8*)p; }

// ---------------------------------------------------------------------------
// GEMM: out(M x NOUT) = A(M x 1024) @ W(NOUT x 1024)^T    (W fp32, A = AT)
// MODE 0: scatter to q/k/v (B,H,N,D) bf16, q scaled by SCALE
// MODE 1: add proj bias (fp32), write fp32 row-major (M x NOUT)
// ---------------------------------------------------------------------------
template <typename AT, int NOUT, int MODE>
__global__ __launch_bounds__(256, 2) void gemm_kernel(
    const AT* __restrict__ A, const float* __restrict__ W,
    const float* __restrict__ pb, bf16* __restrict__ qd, bf16* __restrict__ kd,
    bf16* __restrict__ vd, float* __restrict__ outd) {
    constexpr int Kdim = 1024;
    constexpr int KP = 48;  // LDS row pad (bf16 elems), 96B = 16B-aligned rows
    __shared__ bf16 As[128 * KP];
    __shared__ bf16 Bs[128 * KP];

    const int tid = threadIdx.x;
    const int wave = tid >> 6, lane = tid & 63;
    const int quad = lane >> 4, l16 = lane & 15;
    const int m0 = blockIdx.y * 128;
    const int n0 = blockIdx.x * 128;
    const int wm = (wave >> 1) * 64, wn = (wave & 1) * 64;

    // staging: 512 chunks of 8 elems per tile; thread handles chunks tid, tid+256
    const int r0 = tid >> 2, k8_0 = (tid & 3) * 8;
    const int r1 = (tid + 256) >> 2, k8_1 = ((tid + 256) & 3) * 8;

    f32x4 acc[4][4];
    for (int mi = 0; mi < 4; ++mi)
        for (int ni = 0; ni < 4; ++ni) acc[mi][ni] = fzero4();

    for (int kb = 0; kb < Kdim; kb += 32) {
        __syncthreads();
        {  // stage A (bounds-checked on M)
            bf16x8 va = bzero8();
            int gm = m0 + r0;
            if (gm < M_ROWS) va = load8(A + (size_t)gm * Kdim + kb + k8_0);
            *(bf16x8*)(As + r0 * KP + k8_0) = va;
            bf16x8 vb = bzero8();
            gm = m0 + r1;
            if (gm < M_ROWS) vb = load8(A + (size_t)gm * Kdim + kb + k8_1);
            *(bf16x8*)(As + r1 * KP + k8_1) = vb;
        }
        {  // stage B = W rows (N x K row-major; NOUT multiple of 128, no bounds)
            bf16x8 va = load8(W + (size_t)(n0 + r0) * Kdim + kb + k8_0);
            *(bf16x8*)(Bs + r0 * KP + k8_0) = va;
            bf16x8 vb = load8(W + (size_t)(n0 + r1) * Kdim + kb + k8_1);
            *(bf16x8*)(Bs + r1 * KP + k8_1) = vb;
        }
        __syncthreads();

        bf16x8 af[4], bfr[4];
        for (int mi = 0; mi < 4; ++mi)
            af[mi] = *(const bf16x8*)(As + (wm + mi * 16 + l16) * KP + quad * 8);
        for (int ni = 0; ni < 4; ++ni)
            bfr[ni] = *(const bf16x8*)(Bs + (wn + ni * 16 + l16) * KP + quad * 8);
        for (int mi = 0; mi < 4; ++mi)
            for (int ni = 0; ni < 4; ++ni)
                acc[mi][ni] = MFMA16(af[mi], bfr[ni], acc[mi][ni]);
    }

    // epilogue: C/D layout col=l16, row=quad*4+r
    for (int mi = 0; mi < 4; ++mi) {
        for (int r = 0; r < 4; ++r) {
            int gm = m0 + wm + mi * 16 + quad * 4 + r;
            if (gm >= M_ROWS) continue;
            int bb = gm / Nn;
            int nn = gm - bb * Nn;
            for (int ni = 0; ni < 4; ++ni) {
                int gn = n0 + wn + ni * 16 + l16;
                float val = acc[mi][ni][r];
                if (MODE == 0) {
                    int which = gn >> 10;
                    int hh = (gn >> 6) & 15;
                    int dd = gn & 63;
                    size_t dst = ((size_t)(bb * Hh + hh) * Nn + nn) * Dd + dd;
                    if (which == 0)
                        qd[dst] = (bf16)(val * SCALE);
                    else if (which == 1)
                        kd[dst] = (bf16)val;
                    else
                        vd[dst] = (bf16)val;
                } else {
                    outd[(size_t)gm * NOUT + gn] = val + pb[gn];
                }
            }
        }
    }
}

// ---------------------------------------------------------------------------
// Flash attention: one block = (b, h, 64 q-rows); 4 waves x 16 q-rows each.
// Online softmax over 32 kv-tiles of 64. Bias added from global (fp32).
// ---------------------------------------------------------------------------
__global__ __launch_bounds__(256, 2) void attn_kernel(
    const bf16* __restrict__ q, const bf16* __restrict__ kk,
    const bf16* __restrict__ v, const float* __restrict__ bias,
    bf16* __restrict__ out) {
    __shared__ bf16 Qs[64 * 72];
    __shared__ bf16 Ks[64 * 72];
    __shared__ bf16 VTs[64 * 72];  // [d][kv]
    __shared__ bf16 Ps[64 * 72];

    const int tid = threadIdx.x;
    const int wave = tid >> 6, lane = tid & 63;
    const int quad = lane >> 4, l16 = lane & 15;
    const int b = blockIdx.x, qt = blockIdx.y, h = blockIdx.z;
    const int q0 = qt * 64;
    const int wq0 = wave * 16;

    const size_t head_off = (size_t)(b * Hh + h) * Nn * Dd;
    const bf16* qh = q + head_off;
    const bf16* kh = kk + head_off;
    const bf16* vh = v + head_off;
    const float* biash = bias + (size_t)h * Nn * Nn;

    // stage Q tile once (64 rows x 64 d)
    {
        int c = tid;
        for (int it = 0; it < 2; ++it, c += 256) {
            int row = c >> 3, d8 = (c & 7) * 8;
            bf16x8 vq = bzero8();
            int gq = q0 + row;
            if (gq < Nn) vq = *(const bf16x8*)(qh + (size_t)gq * Dd + d8);
            *(bf16x8*)(Qs + row * 72 + d8) = vq;
        }
    }

    f32x4 acc_o[4];
    for (int nd = 0; nd < 4; ++nd) acc_o[nd] = fzero4();
    float m_prev[4], l_prev[4];
    for (int r = 0; r < 4; ++r) {
        m_prev[r] = NEG_BIG;
        l_prev[r] = 0.f;
    }

    for (int t = 0; t < 32; ++t) {
        const int kv0 = t * 64;
        __syncthreads();  // prior iter's LDS reads done
        {                 // stage K tile and transposed V tile
            int c = tid;
            for (int it = 0; it < 2; ++it, c += 256) {
                int row = c >> 3, d8 = (c & 7) * 8;
                int gk = kv0 + row;
                bf16x8 vk = bzero8(), vv = bzero8();
                if (gk < Nn) {
                    vk = *(const bf16x8*)(kh + (size_t)gk * Dd + d8);
                    vv = *(const bf16x8*)(vh + (size_t)gk * Dd + d8);
                }
                *(bf16x8*)(Ks + row * 72 + d8) = vk;
                for (int j = 0; j < 8; ++j) VTs[(d8 + j) * 72 + row] = vv[j];
            }
        }
        __syncthreads();

        // S = Q K^T (wave's 16 q-rows x 64 kv-cols)
        f32x4 accs[4];
        for (int ni = 0; ni < 4; ++ni) accs[ni] = fzero4();
        bf16x8 aq0 = *(const bf16x8*)(Qs + (wq0 + l16) * 72 + quad * 8);
        bf16x8 aq1 = *(const bf16x8*)(Qs + (wq0 + l16) * 72 + 32 + quad * 8);
        for (int ni = 0; ni < 4; ++ni) {
            bf16x8 bk0 = *(const bf16x8*)(Ks + (ni * 16 + l16) * 72 + quad * 8);
            bf16x8 bk1 = *(const bf16x8*)(Ks + (ni * 16 + l16) * 72 + 32 + quad * 8);
            accs[ni] = MFMA16(aq0, bk0, accs[ni]);
            accs[ni] = MFMA16(aq1, bk1, accs[ni]);
        }

        // add bias (fp32), mask OOB kv columns with finite sentinel
        float s[4][4];
        for (int ni = 0; ni < 4; ++ni) {
            int gkv = kv0 + ni * 16 + l16;
            bool colok = gkv < Nn;
            for (int r = 0; r < 4; ++r) {
                int gq = q0 + wq0 + quad * 4 + r;
                int bq = gq < Nn ? gq : Nn - 1;
                float bv = colok ? biash[(size_t)bq * Nn + gkv] : 0.f;
                s[ni][r] = colok ? accs[ni][r] + bv : NEG_BIG;
            }
        }

        // online softmax per q-row (row = quad*4+r; 16 cols live in this quad)
        float alpha[4];
        for (int r = 0; r < 4; ++r) {
            float mx = fmaxf(fmaxf(s[0][r], s[1][r]), fmaxf(s[2][r], s[3][r]));
            mx = fmaxf(mx, __shfl_xor(mx, 1));
            mx = fmaxf(mx, __shfl_xor(mx, 2));
            mx = fmaxf(mx, __shfl_xor(mx, 4));
            mx = fmaxf(mx, __shfl_xor(mx, 8));
            float mnew = fmaxf(m_prev[r], mx);
            alpha[r] = __expf(m_prev[r] - mnew);
            float rs = 0.f;
            for (int ni = 0; ni < 4; ++ni) {
                float p = __expf(s[ni][r] - mnew);
                s[ni][r] = p;
                rs += p;
            }
            rs += __shfl_xor(rs, 1);
            rs += __shfl_xor(rs, 2);
            rs += __shfl_xor(rs, 4);
            rs += __shfl_xor(rs, 8);
            l_prev[r] = l_prev[r] * alpha[r] + rs;
            m_prev[r] = mnew;
        }

        // rescale O, dump P (C/D layout) to LDS for A-layout reload
        for (int nd = 0; nd < 4; ++nd)
            for (int r = 0; r < 4; ++r) acc_o[nd][r] *= alpha[r];
        for (int ni = 0; ni < 4; ++ni)
            for (int r = 0; r < 4; ++r)
                Ps[(wq0 + quad * 4 + r) * 72 + ni * 16 + l16] = (bf16)s[ni][r];
        __syncthreads();

        // O += P @ V   (B-frags from transposed V: contiguous reads)
        bf16x8 ap0 = *(const bf16x8*)(Ps + (wq0 + l16) * 72 + quad * 8);
        bf16x8 ap1 = *(const bf16x8*)(Ps + (wq0 + l16) * 72 + 32 + quad * 8);
        for (int nd = 0; nd < 4; ++nd) {
            bf16x8 bv0 = *(const bf16x8*)(VTs + (nd * 16 + l16) * 72 + quad * 8);
            bf16x8 bv1 = *(const bf16x8*)(VTs + (nd * 16 + l16) * 72 + 32 + quad * 8);
            acc_o[nd] = MFMA16(ap0, bv0, acc_o[nd]);
            acc_o[nd] = MFMA16(ap1, bv1, acc_o[nd]);
        }
    }

    // write attn_out (B, N, C) bf16 to workspace
    for (int nd = 0; nd < 4; ++nd) {
        for (int r = 0; r < 4; ++r) {
            int gq = q0 + wq0 + quad * 4 + r;
            if (gq >= Nn) continue;
            float val = acc_o[nd][r] / l_prev[r];
            out[((size_t)b * Nn + gq) * Cc + h * 64 + nd * 16 + l16] = (bf16)val;
        }
    }
}

extern "C" void kernel_launch(void* const* d_in, const int* in_sizes, int n_in,
                              void* d_out, int out_size, void* d_ws,
                              size_t ws_size, hipStream_t stream) {
    const float* x = (const float*)d_in[0];
    const float* qkv_w = (const float*)d_in[1];
    const float* proj_w = (const float*)d_in[2];
    const float* proj_b = (const float*)d_in[3];
    const float* bias = (const float*)d_in[4];
    float* out = (float*)d_out;

    const size_t per = (size_t)Bb * Hh * Nn * Dd;  // 8,384,512 elems
    bf16* qd = (bf16*)d_ws;
    bf16* kd = qd + per;
    bf16* vd = kd + per;
    bf16* ao = vd + per;  // attn output (B,N,C) bf16

    // diagnostic (host-side, capture-safe): verify ws budget & input sizes
    const size_t need = 4 * per * sizeof(bf16);
    fprintf(stderr, "[kl] ws_size=%zu need=%zu out_size=%d in_sizes=", ws_size,
            need, out_size);
    for (int i = 0; i < n_in; ++i) fprintf(stderr, "%d,", in_sizes[i]);
    fprintf(stderr, "\n");

    // 1) QKV projection -> q (scaled), k, v in (B,H,N,D) bf16
    gemm_kernel<float, 3072, 0><<<dim3(24, 64), 256, 0, stream>>>(
        x, qkv_w, nullptr, qd, kd, vd, nullptr);
    // 2) flash attention with additive fp32 bias; blockIdx.x = batch so the 4
    //    batches sharing bias[h] run concurrently (LLC reuse)
    attn_kernel<<<dim3(4, 32, 16), 256, 0, stream>>>(qd, kd, vd, bias, ao);
    // 3) output projection + bias -> fp32 out
    gemm_kernel<bf16, 1024, 1><<<dim3(8, 64), 256, 0, stream>>>(
        ao, proj_w, proj_b, nullptr, nullptr, nullptr, out);
}

// Round 3
// 792.225 us; speedup vs baseline: 1.0941x; 1.0941x over previous
//
#include <hip/hip_runtime.h>
#include <hip/hip_bf16.h>
#include <cstdio>

typedef __bf16 bf16;
typedef __attribute__((ext_vector_type(8))) __bf16 bf16x8;
typedef __attribute__((ext_vector_type(4))) float f32x4;

#define MFMA16(a, b, c) __builtin_amdgcn_mfma_f32_16x16x32_bf16((a), (b), (c), 0, 0, 0)

constexpr int Bb = 4, Nn = 2047, Cc = 1024, Hh = 16, Dd = 64;
constexpr int M_ROWS = Bb * Nn;      // 8188
constexpr int NPAD = 2048;           // padded kv stride for V^T
constexpr float SCALE = 0.125f;      // D^-0.5
constexpr float NEG_BIG = -1e30f;    // finite sentinel (no inf anywhere)

__device__ inline bf16x8 bzero8() {
    bf16x8 v;
    for (int i = 0; i < 8; ++i) v[i] = (bf16)0.0f;
    return v;
}
__device__ inline f32x4 fzero4() {
    f32x4 v = {0.f, 0.f, 0.f, 0.f};
    return v;
}

// async global->LDS DMA, 16 B per lane; LDS dest = wave-uniform base + lane*16
__device__ __forceinline__ void async_copy16(const void* g, void* l) {
    __builtin_amdgcn_global_load_lds(
        (const __attribute__((address_space(1))) unsigned int*)g,
        (__attribute__((address_space(3))) unsigned int*)l, 16, 0, 0);
}

// ---------------------------------------------------------------------------
// fp32 -> bf16 convert for x, qkv_w, proj_w (one launch)
// ---------------------------------------------------------------------------
__global__ __launch_bounds__(256) void cvt3_kernel(
    const float* __restrict__ a, bf16* __restrict__ oa, int na8,
    const float* __restrict__ b, bf16* __restrict__ ob, int nb8,
    const float* __restrict__ c, bf16* __restrict__ oc, int nc8) {
    int i = blockIdx.x * blockDim.x + threadIdx.x;
    const float* src;
    bf16* dst;
    int j = i;
    if (j < na8) {
        src = a; dst = oa;
    } else {
        j -= na8;
        if (j < nb8) {
            src = b; dst = ob;
        } else {
            j -= nb8;
            if (j >= nc8) return;
            src = c; dst = oc;
        }
    }
    float4 x0 = ((const float4*)src)[2 * (size_t)j];
    float4 x1 = ((const float4*)src)[2 * (size_t)j + 1];
    bf16x8 v;
    v[0] = (bf16)x0.x; v[1] = (bf16)x0.y; v[2] = (bf16)x0.z; v[3] = (bf16)x0.w;
    v[4] = (bf16)x1.x; v[5] = (bf16)x1.y; v[6] = (bf16)x1.z; v[7] = (bf16)x1.w;
    *(bf16x8*)(dst + 8 * (size_t)j) = v;
}

// ---------------------------------------------------------------------------
// V (B,H,N,D) -> V^T (B,H,D,NPAD), zero-padded at n >= Nn. Runs once.
// ---------------------------------------------------------------------------
__global__ __launch_bounds__(256) void transpose_v_kernel(
    const bf16* __restrict__ vd, bf16* __restrict__ vtd) {
    __shared__ bf16 t[64 * 72];
    const int bh = blockIdx.x, nt = blockIdx.y;
    const int tid = threadIdx.x;
    const bf16* src = vd + (size_t)bh * Nn * Dd;
    bf16* dst = vtd + (size_t)bh * Dd * NPAD;
    int c = tid;
    for (int it = 0; it < 2; ++it, c += 256) {
        int row = c >> 3, d8 = (c & 7) * 8;
        int gn = nt * 64 + row;
        bf16x8 v = bzero8();
        if (gn < Nn) v = *(const bf16x8*)(src + (size_t)gn * Dd + d8);
        *(bf16x8*)(t + row * 72 + d8) = v;
    }
    __syncthreads();
    c = tid;
    for (int it = 0; it < 2; ++it, c += 256) {
        int d = c >> 3, j8 = (c & 7) * 8;
        bf16x8 v;
        for (int k = 0; k < 8; ++k) v[k] = t[(j8 + k) * 72 + d];
        *(bf16x8*)(dst + (size_t)d * NPAD + nt * 64 + j8) = v;
    }
}

// ---------------------------------------------------------------------------
// GEMM (m97 structure): out(M x NOUT) = A(M x 1024) @ W(NOUT x 1024)^T
// A, W bf16. BK=32, unpadded LDS, global_load_lds width-16 staging.
// MODE 0: scatter to q/k/v (B,H,N,D) bf16, q scaled by SCALE
// MODE 1: add proj bias (fp32), write fp32 row-major (M x NOUT)
// ---------------------------------------------------------------------------
template <int NOUT, int MODE>
__global__ __launch_bounds__(256, 2) void gemm_kernel(
    const bf16* __restrict__ A, const bf16* __restrict__ W,
    const float* __restrict__ pb, bf16* __restrict__ qd, bf16* __restrict__ kd,
    bf16* __restrict__ vd, float* __restrict__ outd) {
    constexpr int Kdim = 1024;
    __shared__ bf16 As[128 * 32];
    __shared__ bf16 Bs[128 * 32];

    const int tid = threadIdx.x;
    const int wave = tid >> 6, lane = tid & 63;
    const int quad = lane >> 4, l16 = lane & 15;
    const int m0 = blockIdx.y * 128;
    const int n0 = blockIdx.x * 128;
    const int wm = (wave >> 1) * 64, wn = (wave & 1) * 64;

    // DMA lane mapping: per instr 64 lanes x 16B = 16 rows x 64B (32 bf16)
    const int dma_r = lane >> 2;          // row within 16-row group
    const int dma_k = (lane & 3) * 8;     // elem offset within row

    f32x4 acc[4][4];
    for (int mi = 0; mi < 4; ++mi)
        for (int ni = 0; ni < 4; ++ni) acc[mi][ni] = fzero4();

    for (int kb = 0; kb < Kdim; kb += 32) {
        __syncthreads();
        // stage A: 8 instrs (2/wave), rows clamped (dup rows discarded later)
        for (int i = 0; i < 2; ++i) {
            int g = wave * 2 + i;                 // 16-row group 0..7
            int row = g * 16 + dma_r;
            int gm = m0 + row;
            if (gm > M_ROWS - 1) gm = M_ROWS - 1;
            async_copy16(A + (size_t)gm * Kdim + kb + dma_k, As + g * 16 * 32);
        }
        // stage B: W rows (NOUT multiple of 128, no bounds)
        for (int i = 0; i < 2; ++i) {
            int g = wave * 2 + i;
            int row = g * 16 + dma_r;
            async_copy16(W + (size_t)(n0 + row) * Kdim + kb + dma_k,
                         Bs + g * 16 * 32);
        }
        __syncthreads();

        bf16x8 af[4], bfr[4];
        for (int mi = 0; mi < 4; ++mi)
            af[mi] = *(const bf16x8*)(As + (wm + mi * 16 + l16) * 32 + quad * 8);
        for (int ni = 0; ni < 4; ++ni)
            bfr[ni] = *(const bf16x8*)(Bs + (wn + ni * 16 + l16) * 32 + quad * 8);
        for (int mi = 0; mi < 4; ++mi)
            for (int ni = 0; ni < 4; ++ni)
                acc[mi][ni] = MFMA16(af[mi], bfr[ni], acc[mi][ni]);
    }

    // epilogue: C/D layout col=l16, row=quad*4+r
    for (int mi = 0; mi < 4; ++mi) {
        for (int r = 0; r < 4; ++r) {
            int gm = m0 + wm + mi * 16 + quad * 4 + r;
            if (gm >= M_ROWS) continue;
            int bb = gm / Nn;
            int nn = gm - bb * Nn;
            for (int ni = 0; ni < 4; ++ni) {
                int gn = n0 + wn + ni * 16 + l16;
                float val = acc[mi][ni][r];
                if (MODE == 0) {
                    int which = gn >> 10;
                    int hh = (gn >> 6) & 15;
                    int dd = gn & 63;
                    size_t dst = ((size_t)(bb * Hh + hh) * Nn + nn) * Dd + dd;
                    if (which == 0)
                        qd[dst] = (bf16)(val * SCALE);
                    else if (which == 1)
                        kd[dst] = (bf16)val;
                    else
                        vd[dst] = (bf16)val;
                } else {
                    outd[(size_t)gm * NOUT + gn] = val + pb[gn];
                }
            }
        }
    }
}

// ---------------------------------------------------------------------------
// Flash attention: block = (b, qt, h), 64 q-rows, 4 waves x 16 q-rows.
// Online softmax over 32 kv-tiles of 64. Bias tile staged via async DMA.
// V comes pre-transposed (B,H,D,NPAD) -> coalesced b128 staging.
// ---------------------------------------------------------------------------
__global__ __launch_bounds__(256, 3) void attn_kernel(
    const bf16* __restrict__ q, const bf16* __restrict__ kk,
    const bf16* __restrict__ vt, const float* __restrict__ bias,
    bf16* __restrict__ out) {
    __shared__ bf16 Qs[64 * 72];
    __shared__ bf16 Ks[64 * 72];
    __shared__ bf16 VTs[64 * 72];   // [d][kv]
    __shared__ bf16 Ps[64 * 72];    // wave-private rows
    __shared__ float BiasS[64 * 64];

    const int tid = threadIdx.x;
    const int wave = tid >> 6, lane = tid & 63;
    const int quad = lane >> 4, l16 = lane & 15;
    const int b = blockIdx.x, qt = blockIdx.y, h = blockIdx.z;
    const int q0 = qt * 64;
    const int wq0 = wave * 16;

    const size_t head_off = (size_t)(b * Hh + h) * Nn * Dd;
    const bf16* qh = q + head_off;
    const bf16* kh = kk + head_off;
    const bf16* vth = vt + (size_t)(b * Hh + h) * Dd * NPAD;
    const float* biash = bias + (size_t)h * Nn * Nn;

    // stage Q tile once (64 rows x 64 d)
    {
        int c = tid;
        for (int it = 0; it < 2; ++it, c += 256) {
            int row = c >> 3, d8 = (c & 7) * 8;
            bf16x8 vq = bzero8();
            int gq = q0 + row;
            if (gq < Nn) vq = *(const bf16x8*)(qh + (size_t)gq * Dd + d8);
            *(bf16x8*)(Qs + row * 72 + d8) = vq;
        }
    }

    f32x4 acc_o[4];
    for (int nd = 0; nd < 4; ++nd) acc_o[nd] = fzero4();
    float m_prev[4], l_prev[4];
    for (int r = 0; r < 4; ++r) {
        m_prev[r] = NEG_BIG;
        l_prev[r] = 0.f;
    }

    for (int t = 0; t < 32; ++t) {
        const int kv0 = t * 64;
        __syncthreads();  // prior iter's LDS reads done

        // --- bias tile: async DMA (full tiles) / scalar fallback (tail) ---
        if (kv0 + 64 <= Nn) {
            for (int i = 0; i < 4; ++i) {
                int row = wave * 16 + i * 4 + (lane >> 4);
                int gq = q0 + row;
                int bq = gq < Nn ? gq : Nn - 1;
                async_copy16(biash + (size_t)bq * Nn + kv0 + (lane & 15) * 4,
                             BiasS + (wave * 16 + i * 4) * 64);
            }
        } else {
            for (int e = tid; e < 4096; e += 256) {
                int row = e >> 6, col = e & 63;
                int gq = q0 + row;
                int bq = gq < Nn ? gq : Nn - 1;
                int gkv = kv0 + col;
                BiasS[e] = (gkv < Nn) ? biash[(size_t)bq * Nn + gkv] : 0.f;
            }
        }
        // --- stage K tile and (pre-transposed) V^T tile, coalesced b128 ---
        {
            int c = tid;
            for (int it = 0; it < 2; ++it, c += 256) {
                int row = c >> 3, d8 = (c & 7) * 8;
                int gk = kv0 + row;
                bf16x8 vk = bzero8();
                if (gk < Nn) vk = *(const bf16x8*)(kh + (size_t)gk * Dd + d8);
                *(bf16x8*)(Ks + row * 72 + d8) = vk;
                // row = d (always valid); cols kv0+d8..+7 < NPAD, zero-padded
                bf16x8 vv = *(const bf16x8*)(vth + (size_t)row * NPAD + kv0 + d8);
                *(bf16x8*)(VTs + row * 72 + d8) = vv;
            }
        }
        __syncthreads();

        // S = Q K^T (wave's 16 q-rows x 64 kv-cols)
        f32x4 accs[4];
        for (int ni = 0; ni < 4; ++ni) accs[ni] = fzero4();
        bf16x8 aq0 = *(const bf16x8*)(Qs + (wq0 + l16) * 72 + quad * 8);
        bf16x8 aq1 = *(const bf16x8*)(Qs + (wq0 + l16) * 72 + 32 + quad * 8);
        for (int ni = 0; ni < 4; ++ni) {
            bf16x8 bk0 = *(const bf16x8*)(Ks + (ni * 16 + l16) * 72 + quad * 8);
            bf16x8 bk1 = *(const bf16x8*)(Ks + (ni * 16 + l16) * 72 + 32 + quad * 8);
            accs[ni] = MFMA16(aq0, bk0, accs[ni]);
            accs[ni] = MFMA16(aq1, bk1, accs[ni]);
        }

        // add bias (from LDS), mask OOB kv columns with finite sentinel
        float s[4][4];
        for (int ni = 0; ni < 4; ++ni) {
            int gkv = kv0 + ni * 16 + l16;
            bool colok = gkv < Nn;
            for (int r = 0; r < 4; ++r) {
                float bv = BiasS[(wq0 + quad * 4 + r) * 64 + ni * 16 + l16];
                s[ni][r] = colok ? accs[ni][r] + bv : NEG_BIG;
            }
        }

        // online softmax per q-row (row = quad*4+r; 16 cols live in this quad)
        float alpha[4];
        for (int r = 0; r < 4; ++r) {
            float mx = fmaxf(fmaxf(s[0][r], s[1][r]), fmaxf(s[2][r], s[3][r]));
            mx = fmaxf(mx, __shfl_xor(mx, 1));
            mx = fmaxf(mx, __shfl_xor(mx, 2));
            mx = fmaxf(mx, __shfl_xor(mx, 4));
            mx = fmaxf(mx, __shfl_xor(mx, 8));
            float mnew = fmaxf(m_prev[r], mx);
            alpha[r] = __expf(m_prev[r] - mnew);
            float rs = 0.f;
            for (int ni = 0; ni < 4; ++ni) {
                float p = __expf(s[ni][r] - mnew);
                s[ni][r] = p;
                rs += p;
            }
            rs += __shfl_xor(rs, 1);
            rs += __shfl_xor(rs, 2);
            rs += __shfl_xor(rs, 4);
            rs += __shfl_xor(rs, 8);
            l_prev[r] = l_prev[r] * alpha[r] + rs;
            m_prev[r] = mnew;
        }

        // rescale O, dump P (C/D layout) into wave-private Ps rows.
        // No barrier needed: each wave reads back only its own 16 rows.
        for (int nd = 0; nd < 4; ++nd)
            for (int r = 0; r < 4; ++r) acc_o[nd][r] *= alpha[r];
        for (int ni = 0; ni < 4; ++ni)
            for (int r = 0; r < 4; ++r)
                Ps[(wq0 + quad * 4 + r) * 72 + ni * 16 + l16] = (bf16)s[ni][r];

        // O += P @ V   (B-frags from transposed V: contiguous b128 reads)
        bf16x8 ap0 = *(const bf16x8*)(Ps + (wq0 + l16) * 72 + quad * 8);
        bf16x8 ap1 = *(const bf16x8*)(Ps + (wq0 + l16) * 72 + 32 + quad * 8);
        for (int nd = 0; nd < 4; ++nd) {
            bf16x8 bv0 = *(const bf16x8*)(VTs + (nd * 16 + l16) * 72 + quad * 8);
            bf16x8 bv1 = *(const bf16x8*)(VTs + (nd * 16 + l16) * 72 + 32 + quad * 8);
            acc_o[nd] = MFMA16(ap0, bv0, acc_o[nd]);
            acc_o[nd] = MFMA16(ap1, bv1, acc_o[nd]);
        }
    }

    // write attn_out (B, N, C) bf16 to workspace
    for (int nd = 0; nd < 4; ++nd) {
        for (int r = 0; r < 4; ++r) {
            int gq = q0 + wq0 + quad * 4 + r;
            if (gq >= Nn) continue;
            float val = acc_o[nd][r] / l_prev[r];
            out[((size_t)b * Nn + gq) * Cc + h * 64 + nd * 16 + l16] = (bf16)val;
        }
    }
}

extern "C" void kernel_launch(void* const* d_in, const int* in_sizes, int n_in,
                              void* d_out, int out_size, void* d_ws,
                              size_t ws_size, hipStream_t stream) {
    const float* x = (const float*)d_in[0];
    const float* qkv_w = (const float*)d_in[1];
    const float* proj_w = (const float*)d_in[2];
    const float* proj_b = (const float*)d_in[3];
    const float* bias = (const float*)d_in[4];
    float* out = (float*)d_out;

    const size_t per = (size_t)Bb * Hh * Nn * Dd;     // 8,384,512
    const size_t nx = (size_t)M_ROWS * Cc;            // 8,384,512
    const size_t nqw = (size_t)3 * Cc * Cc;           // 3,145,728
    const size_t npw = (size_t)Cc * Cc;               // 1,048,576
    const size_t nvt = (size_t)Bb * Hh * Dd * NPAD;   // 8,388,608

    // ws layout (bf16 elems): [qkvwb][projwb][qd][kd][vd][ao][R: xb then vtd]
    bf16* qkvwb = (bf16*)d_ws;
    bf16* projwb = qkvwb + nqw;
    bf16* qd = projwb + npw;
    bf16* kd = qd + per;
    bf16* vd = kd + per;
    bf16* ao = vd + per;
    bf16* xb = ao + nx;        // region R: x (bf16) until QKV GEMM done...
    bf16* vtd = ao + nx;       // ...then reused for V^T (16.8 MB)

    const size_t need = (nqw + npw + 3 * per + nx + (nvt > nx ? nvt : nx)) * 2;
    fprintf(stderr, "[kl] ws_size=%zu need=%zu\n", ws_size, need);

    // 0) convert x, qkv_w, proj_w to bf16
    {
        int na8 = (int)(nx / 8), nb8 = (int)(nqw / 8), nc8 = (int)(npw / 8);
        int tot = na8 + nb8 + nc8;
        cvt3_kernel<<<(tot + 255) / 256, 256, 0, stream>>>(
            x, xb, na8, qkv_w, qkvwb, nb8, proj_w, projwb, nc8);
    }
    // 1) QKV projection -> q (scaled), k, v in (B,H,N,D) bf16
    gemm_kernel<3072, 0><<<dim3(24, 64), 256, 0, stream>>>(
        xb, qkvwb, nullptr, qd, kd, vd, nullptr);
    // 2) V -> V^T (B,H,D,NPAD), zero-padded (overwrites xb region; xb is dead)
    transpose_v_kernel<<<dim3(64, 32), 256, 0, stream>>>(vd, vtd);
    // 3) flash attention; blockIdx.x = batch for bias LLC reuse
    attn_kernel<<<dim3(4, 32, 16), 256, 0, stream>>>(qd, kd, vtd, bias, ao);
    // 4) output projection + bias -> fp32 out
    gemm_kernel<1024, 1><<<dim3(8, 64), 256, 0, stream>>>(
        ao, projwb, proj_b, nullptr, nullptr, nullptr, out);
}

// Round 4
// 686.072 us; speedup vs baseline: 1.2634x; 1.1547x over previous
//
#include <hip/hip_runtime.h>
#include <hip/hip_bf16.h>

typedef __bf16 bf16;
typedef __attribute__((ext_vector_type(8))) __bf16 bf16x8;
typedef __attribute__((ext_vector_type(4))) __bf16 bf16x4;
typedef __attribute__((ext_vector_type(4))) float f32x4;

#define MFMA16(a, b, c) __builtin_amdgcn_mfma_f32_16x16x32_bf16((a), (b), (c), 0, 0, 0)

constexpr int Bb = 4, Nn = 2047, Cc = 1024, Hh = 16, Dd = 64;
constexpr int M_ROWS = Bb * Nn;      // 8188
constexpr int NPAD = 2048;           // padded kv stride for V^T
constexpr float SCALE = 0.125f;      // D^-0.5
constexpr float NEG_BIG = -1e30f;    // finite sentinel (no inf anywhere)

__device__ inline bf16x8 bzero8() {
    bf16x8 v;
    for (int i = 0; i < 8; ++i) v[i] = (bf16)0.0f;
    return v;
}
__device__ inline bf16x8 bones8() {
    bf16x8 v;
    for (int i = 0; i < 8; ++i) v[i] = (bf16)1.0f;
    return v;
}
__device__ inline f32x4 fzero4() {
    f32x4 v = {0.f, 0.f, 0.f, 0.f};
    return v;
}

// async global->LDS DMA, 16 B per lane; LDS dest = wave-uniform base + lane*16
__device__ __forceinline__ void async_copy16(const void* g, void* l) {
    __builtin_amdgcn_global_load_lds(
        (const __attribute__((address_space(1))) unsigned int*)g,
        (__attribute__((address_space(3))) unsigned int*)l, 16, 0, 0);
}

// ---------------------------------------------------------------------------
// fp32 -> bf16 convert for x, qkv_w, proj_w (one launch)
// ---------------------------------------------------------------------------
__global__ __launch_bounds__(256) void cvt3_kernel(
    const float* __restrict__ a, bf16* __restrict__ oa, int na8,
    const float* __restrict__ b, bf16* __restrict__ ob, int nb8,
    const float* __restrict__ c, bf16* __restrict__ oc, int nc8) {
    int i = blockIdx.x * blockDim.x + threadIdx.x;
    const float* src;
    bf16* dst;
    int j = i;
    if (j < na8) {
        src = a; dst = oa;
    } else {
        j -= na8;
        if (j < nb8) {
            src = b; dst = ob;
        } else {
            j -= nb8;
            if (j >= nc8) return;
            src = c; dst = oc;
        }
    }
    float4 x0 = ((const float4*)src)[2 * (size_t)j];
    float4 x1 = ((const float4*)src)[2 * (size_t)j + 1];
    bf16x8 v;
    v[0] = (bf16)x0.x; v[1] = (bf16)x0.y; v[2] = (bf16)x0.z; v[3] = (bf16)x0.w;
    v[4] = (bf16)x1.x; v[5] = (bf16)x1.y; v[6] = (bf16)x1.z; v[7] = (bf16)x1.w;
    *(bf16x8*)(dst + 8 * (size_t)j) = v;
}

// ---------------------------------------------------------------------------
// V (B,H,N,D) -> V^T (B,H,D,NPAD), zero-padded at n >= Nn. Runs once.
// ---------------------------------------------------------------------------
__global__ __launch_bounds__(256) void transpose_v_kernel(
    const bf16* __restrict__ vd, bf16* __restrict__ vtd) {
    __shared__ bf16 t[64 * 72];
    const int bh = blockIdx.x, nt = blockIdx.y;
    const int tid = threadIdx.x;
    const bf16* src = vd + (size_t)bh * Nn * Dd;
    bf16* dst = vtd + (size_t)bh * Dd * NPAD;
    int c = tid;
    for (int it = 0; it < 2; ++it, c += 256) {
        int row = c >> 3, d8 = (c & 7) * 8;
        int gn = nt * 64 + row;
        bf16x8 v = bzero8();
        if (gn < Nn) v = *(const bf16x8*)(src + (size_t)gn * Dd + d8);
        *(bf16x8*)(t + row * 72 + d8) = v;
    }
    __syncthreads();
    c = tid;
    for (int it = 0; it < 2; ++it, c += 256) {
        int d = c >> 3, j8 = (c & 7) * 8;
        bf16x8 v;
        for (int k = 0; k < 8; ++k) v[k] = t[(j8 + k) * 72 + d];
        *(bf16x8*)(dst + (size_t)d * NPAD + nt * 64 + j8) = v;
    }
}

// ---------------------------------------------------------------------------
// GEMM (m97 structure): out(M x NOUT) = A(M x 1024) @ W(NOUT x 1024)^T
// ---------------------------------------------------------------------------
template <int NOUT, int MODE>
__global__ __launch_bounds__(256, 2) void gemm_kernel(
    const bf16* __restrict__ A, const bf16* __restrict__ W,
    const float* __restrict__ pb, bf16* __restrict__ qd, bf16* __restrict__ kd,
    bf16* __restrict__ vd, float* __restrict__ outd) {
    constexpr int Kdim = 1024;
    __shared__ bf16 As[128 * 32];
    __shared__ bf16 Bs[128 * 32];

    const int tid = threadIdx.x;
    const int wave = tid >> 6, lane = tid & 63;
    const int quad = lane >> 4, l16 = lane & 15;
    const int m0 = blockIdx.y * 128;
    const int n0 = blockIdx.x * 128;
    const int wm = (wave >> 1) * 64, wn = (wave & 1) * 64;

    const int dma_r = lane >> 2;          // row within 16-row group
    const int dma_k = (lane & 3) * 8;     // elem offset within row

    f32x4 acc[4][4];
    for (int mi = 0; mi < 4; ++mi)
        for (int ni = 0; ni < 4; ++ni) acc[mi][ni] = fzero4();

    for (int kb = 0; kb < Kdim; kb += 32) {
        __syncthreads();
        for (int i = 0; i < 2; ++i) {
            int g = wave * 2 + i;                 // 16-row group 0..7
            int row = g * 16 + dma_r;
            int gm = m0 + row;
            if (gm > M_ROWS - 1) gm = M_ROWS - 1;
            async_copy16(A + (size_t)gm * Kdim + kb + dma_k, As + g * 16 * 32);
        }
        for (int i = 0; i < 2; ++i) {
            int g = wave * 2 + i;
            int row = g * 16 + dma_r;
            async_copy16(W + (size_t)(n0 + row) * Kdim + kb + dma_k,
                         Bs + g * 16 * 32);
        }
        __syncthreads();

        bf16x8 af[4], bfr[4];
        for (int mi = 0; mi < 4; ++mi)
            af[mi] = *(const bf16x8*)(As + (wm + mi * 16 + l16) * 32 + quad * 8);
        for (int ni = 0; ni < 4; ++ni)
            bfr[ni] = *(const bf16x8*)(Bs + (wn + ni * 16 + l16) * 32 + quad * 8);
        for (int mi = 0; mi < 4; ++mi)
            for (int ni = 0; ni < 4; ++ni)
                acc[mi][ni] = MFMA16(af[mi], bfr[ni], acc[mi][ni]);
    }

    for (int mi = 0; mi < 4; ++mi) {
        for (int r = 0; r < 4; ++r) {
            int gm = m0 + wm + mi * 16 + quad * 4 + r;
            if (gm >= M_ROWS) continue;
            int bb = gm / Nn;
            int nn = gm - bb * Nn;
            for (int ni = 0; ni < 4; ++ni) {
                int gn = n0 + wn + ni * 16 + l16;
                float val = acc[mi][ni][r];
                if (MODE == 0) {
                    int which = gn >> 10;
                    int hh = (gn >> 6) & 15;
                    int dd = gn & 63;
                    size_t dst = ((size_t)(bb * Hh + hh) * Nn + nn) * Dd + dd;
                    if (which == 0)
                        qd[dst] = (bf16)(val * SCALE);
                    else if (which == 1)
                        kd[dst] = (bf16)val;
                    else
                        vd[dst] = (bf16)val;
                } else {
                    outd[(size_t)gm * NOUT + gn] = val + pb[gn];
                }
            }
        }
    }
}

// ---------------------------------------------------------------------------
// Flash attention, S^T formulation. Block = (b, qt, h): 64 q-rows, 4 waves
// x 16 q each. Per kv-tile (64): S^T = K.Q^T so each lane owns ONE q-column
// (q = l16): softmax = 16 in-lane values + 2 shuffles. Row-sum l via
// MFMA-with-ones. P lands in natural A-layout -> 4 ds_write_b64 only.
// Bias read per-lane from global (fixed row per lane) - no LDS, no DMA.
// ---------------------------------------------------------------------------
__global__ __launch_bounds__(256, 4) void attn_kernel(
    const bf16* __restrict__ q, const bf16* __restrict__ kk,
    const bf16* __restrict__ vt, const float* __restrict__ bias,
    bf16* __restrict__ out) {
    __shared__ bf16 Qs[64 * 72];
    __shared__ bf16 Ks[64 * 72];
    __shared__ bf16 VTs[64 * 72];   // [d][kv]
    __shared__ bf16 Ps[64 * 72];    // [q][kv], wave-private rows

    const int tid = threadIdx.x;
    const int wave = tid >> 6, lane = tid & 63;
    const int quad = lane >> 4, l16 = lane & 15;
    const int b = blockIdx.x, qt = blockIdx.y, h = blockIdx.z;
    const int q0 = qt * 64;
    const int wq0 = wave * 16;

    const size_t head_off = (size_t)(b * Hh + h) * Nn * Dd;
    const bf16* qh = q + head_off;
    const bf16* kh = kk + head_off;
    const bf16* vth = vt + (size_t)(b * Hh + h) * Dd * NPAD;

    // per-lane fixed bias row: this lane's q-column is q0+wq0+l16
    int gq_lane = q0 + wq0 + l16;
    if (gq_lane > Nn - 1) gq_lane = Nn - 1;
    const float* brow = bias + ((size_t)h * Nn + gq_lane) * Nn;

    // stage Q tile once (64 rows x 64 d)
    {
        int c = tid;
        for (int it = 0; it < 2; ++it, c += 256) {
            int row = c >> 3, d8 = (c & 7) * 8;
            bf16x8 vq = bzero8();
            int gq = q0 + row;
            if (gq < Nn) vq = *(const bf16x8*)(qh + (size_t)gq * Dd + d8);
            *(bf16x8*)(Qs + row * 72 + d8) = vq;
        }
    }
    __syncthreads();
    // hoisted Q B-fragments (loop-invariant): lane supplies Q row wq0+l16
    const bf16x8 bq0 = *(const bf16x8*)(Qs + (wq0 + l16) * 72 + quad * 8);
    const bf16x8 bq1 = *(const bf16x8*)(Qs + (wq0 + l16) * 72 + 32 + quad * 8);
    const bf16x8 ones = bones8();

    f32x4 acc_o[4];     // O in C/D layout: row q=quad*4+r, col d=nd*16+l16
    for (int nd = 0; nd < 4; ++nd) acc_o[nd] = fzero4();
    f32x4 acc_l = fzero4();  // row-sums l, same row layout
    float m_prev = NEG_BIG;  // per-lane: running max for q-column l16

    for (int t = 0; t < 32; ++t) {
        const int kv0 = t * 64;
        __syncthreads();  // prior iter's Ks/VTs reads done

        // bias for this tile: 16 scalar global loads (idle VMEM pipe)
        float bv[4][4];
        for (int mi = 0; mi < 4; ++mi)
            for (int r = 0; r < 4; ++r) {
                int kv = kv0 + mi * 16 + quad * 4 + r;
                bv[mi][r] = (kv < Nn) ? brow[kv] : 0.f;
            }

        // stage K tile and (pre-transposed) V^T tile, coalesced b128
        {
            int c = tid;
            for (int it = 0; it < 2; ++it, c += 256) {
                int row = c >> 3, d8 = (c & 7) * 8;
                int gk = kv0 + row;
                bf16x8 vk = bzero8();
                if (gk < Nn) vk = *(const bf16x8*)(kh + (size_t)gk * Dd + d8);
                *(bf16x8*)(Ks + row * 72 + d8) = vk;
                bf16x8 vv = *(const bf16x8*)(vth + (size_t)row * NPAD + kv0 + d8);
                *(bf16x8*)(VTs + row * 72 + d8) = vv;
            }
        }
        __syncthreads();

        // S^T = K . Q^T : D[kv][q], 4 tiles of 16 kv-rows
        f32x4 sT[4];
        for (int mi = 0; mi < 4; ++mi) sT[mi] = fzero4();
        for (int mi = 0; mi < 4; ++mi) {
            bf16x8 ak0 = *(const bf16x8*)(Ks + (mi * 16 + l16) * 72 + quad * 8);
            bf16x8 ak1 = *(const bf16x8*)(Ks + (mi * 16 + l16) * 72 + 32 + quad * 8);
            sT[mi] = MFMA16(ak0, bq0, sT[mi]);
            sT[mi] = MFMA16(ak1, bq1, sT[mi]);
        }

        // scores + bias, mask OOB kv (per-lane kv = mi*16 + quad*4 + r)
        float s[4][4];
        for (int mi = 0; mi < 4; ++mi)
            for (int r = 0; r < 4; ++r) {
                int kv = kv0 + mi * 16 + quad * 4 + r;
                s[mi][r] = (kv < Nn) ? sT[mi][r] + bv[mi][r] : NEG_BIG;
            }

        // online softmax for q-column l16: in-lane max + xor16/32
        float mx = s[0][0];
        for (int mi = 0; mi < 4; ++mi)
            for (int r = 0; r < 4; ++r) mx = fmaxf(mx, s[mi][r]);
        mx = fmaxf(mx, __shfl_xor(mx, 16));
        mx = fmaxf(mx, __shfl_xor(mx, 32));
        float mnew = fmaxf(m_prev, mx);
        float alpha_col = __expf(m_prev - mnew);
        m_prev = mnew;

        // P = exp(s - m), packed b64 stores into natural A-layout [q][kv]
        for (int mi = 0; mi < 4; ++mi) {
            bf16x4 pv;
            for (int r = 0; r < 4; ++r)
                pv[r] = (bf16)__expf(s[mi][r] - mnew);
            *(bf16x4*)(Ps + (wq0 + l16) * 72 + mi * 16 + quad * 4) = pv;
        }

        // alpha to row layout (q = quad*4+r lives in lane quad*4+r)
        float ar[4];
        for (int r = 0; r < 4; ++r) ar[r] = __shfl(alpha_col, quad * 4 + r);
        for (int nd = 0; nd < 4; ++nd)
            for (int r = 0; r < 4; ++r) acc_o[nd][r] *= ar[r];
        for (int r = 0; r < 4; ++r) acc_l[r] *= ar[r];

        // O += P.V ; l += P.1  (wave-private Ps: no barrier, lgkmcnt only)
        bf16x8 ap0 = *(const bf16x8*)(Ps + (wq0 + l16) * 72 + quad * 8);
        bf16x8 ap1 = *(const bf16x8*)(Ps + (wq0 + l16) * 72 + 32 + quad * 8);
        for (int nd = 0; nd < 4; ++nd) {
            bf16x8 bv0 = *(const bf16x8*)(VTs + (nd * 16 + l16) * 72 + quad * 8);
            bf16x8 bv1 = *(const bf16x8*)(VTs + (nd * 16 + l16) * 72 + 32 + quad * 8);
            acc_o[nd] = MFMA16(ap0, bv0, acc_o[nd]);
            acc_o[nd] = MFMA16(ap1, bv1, acc_o[nd]);
        }
        acc_l = MFMA16(ap0, ones, acc_l);
        acc_l = MFMA16(ap1, ones, acc_l);
    }

    // write attn_out (B, N, C) bf16; l is in matching row layout
    for (int nd = 0; nd < 4; ++nd) {
        for (int r = 0; r < 4; ++r) {
            int gq = q0 + wq0 + quad * 4 + r;
            if (gq >= Nn) continue;
            float val = acc_o[nd][r] / acc_l[r];
            out[((size_t)b * Nn + gq) * Cc + h * 64 + nd * 16 + l16] = (bf16)val;
        }
    }
}

extern "C" void kernel_launch(void* const* d_in, const int* in_sizes, int n_in,
                              void* d_out, int out_size, void* d_ws,
                              size_t ws_size, hipStream_t stream) {
    const float* x = (const float*)d_in[0];
    const float* qkv_w = (const float*)d_in[1];
    const float* proj_w = (const float*)d_in[2];
    const float* proj_b = (const float*)d_in[3];
    const float* bias = (const float*)d_in[4];
    float* out = (float*)d_out;

    const size_t per = (size_t)Bb * Hh * Nn * Dd;     // 8,384,512
    const size_t nx = (size_t)M_ROWS * Cc;            // 8,384,512
    const size_t nqw = (size_t)3 * Cc * Cc;           // 3,145,728
    const size_t npw = (size_t)Cc * Cc;               // 1,048,576

    // ws layout (bf16 elems): [qkvwb][projwb][qd][kd][vd][ao][R: xb then vtd]
    bf16* qkvwb = (bf16*)d_ws;
    bf16* projwb = qkvwb + nqw;
    bf16* qd = projwb + npw;
    bf16* kd = qd + per;
    bf16* vd = kd + per;
    bf16* ao = vd + per;
    bf16* xb = ao + nx;        // region R: x (bf16) until QKV GEMM done...
    bf16* vtd = ao + nx;       // ...then reused for V^T (16.8 MB)

    // 0) convert x, qkv_w, proj_w to bf16
    {
        int na8 = (int)(nx / 8), nb8 = (int)(nqw / 8), nc8 = (int)(npw / 8);
        int tot = na8 + nb8 + nc8;
        cvt3_kernel<<<(tot + 255) / 256, 256, 0, stream>>>(
            x, xb, na8, qkv_w, qkvwb, nb8, proj_w, projwb, nc8);
    }
    // 1) QKV projection -> q (scaled), k, v in (B,H,N,D) bf16
    gemm_kernel<3072, 0><<<dim3(24, 64), 256, 0, stream>>>(
        xb, qkvwb, nullptr, qd, kd, vd, nullptr);
    // 2) V -> V^T (B,H,D,NPAD), zero-padded (overwrites xb region; xb is dead)
    transpose_v_kernel<<<dim3(64, 32), 256, 0, stream>>>(vd, vtd);
    // 3) flash attention (S^T formulation); blockIdx.x = batch for bias reuse
    attn_kernel<<<dim3(4, 32, 16), 256, 0, stream>>>(qd, kd, vtd, bias, ao);
    // 4) output projection + bias -> fp32 out
    gemm_kernel<1024, 1><<<dim3(8, 64), 256, 0, stream>>>(
        ao, projwb, proj_b, nullptr, nullptr, nullptr, out);
}